// Round 9
// baseline (180.380 us; speedup 1.0000x reference)
//
#include <hip/hip_runtime.h>

#define N_FULL 65536
#define NN1    16384
#define NN2    8192

typedef __attribute__((ext_vector_type(8))) short bf16x8;
typedef __attribute__((ext_vector_type(4))) float f32x4;
typedef unsigned short ushortT;

#define MFMA16(acc, a, b) acc = __builtin_amdgcn_mfma_f32_16x16x32_bf16(a, b, acc, 0, 0, 0)

#if __has_builtin(__builtin_amdgcn_cvt_pk_bf16_f32)
typedef __attribute__((ext_vector_type(2))) __bf16 bf16x2t;
static __device__ __forceinline__ unsigned pack2(float a, float b) {
    union { bf16x2t v; unsigned u; } c;
    c.v = __builtin_amdgcn_cvt_pk_bf16_f32(a, b);
    return c.u;
}
static __device__ __forceinline__ ushortT f2bf(float f) {
    union { bf16x2t v; ushortT s[2]; } c;
    c.v = __builtin_amdgcn_cvt_pk_bf16_f32(f, 0.f);
    return c.s[0];
}
#else
static __device__ __forceinline__ ushortT f2bf(float f) {
    union { float f; unsigned u; } v; v.f = f;
    unsigned r = v.u + 0x7FFFu + ((v.u >> 16) & 1u);
    return (ushortT)(r >> 16);
}
static __device__ __forceinline__ unsigned pack2(float a, float b) {
    return (unsigned)f2bf(a) | ((unsigned)f2bf(b) << 16);
}
#endif

static __device__ __forceinline__ float bfu2f(ushortT h) {
    union { unsigned u; float f; } v; v.u = (unsigned)h << 16; return v.f;
}

// ws layout (ushort units) — all byte offsets 16B-aligned
#define WS_WAT1  2304     /* [64][72]   */
#define WS_WGT1  6912     /* [64][72]   */
#define WS_WAT2  11520    /* [128][136] */
#define WS_WGT2  28928    /* [128][136] */
#define WS_WUPT  46336    /* [128][136] */
#define WS_WSCT  63744    /* [128][72]  */
#define WS_H0    73728    /* bf16 [65536][32] */
#define WS_H1    (WS_H0 + 65536u*32u)

// softmax fixed shift: softmax(a) == softmax(a - C); scores are relu'd O(10)
#define SMAX_SHIFT 24.0f

// ---------------------------------------------------------------------------
// weight transpose helper (runs in the prep-blocks of k_down)
// ---------------------------------------------------------------------------
static __device__ __forceinline__ void tpose(
    const float* __restrict__ src, ushortT* __restrict__ dst,
    int K, int N, int STR, int gid, int gs)
{
    for (int i = gid; i < K * N; i += gs) {
        const int n = i / K, k = i - n * K;
        dst[n * STR + k] = f2bf(src[(size_t)k * N + n]);
    }
}

// ---------------------------------------------------------------------------
// k_down (+prep): blocks <512: h0 = relu(x @ Wd + bd); blocks >=512: weight
// transposes for later kernels.
// ---------------------------------------------------------------------------
__global__ __launch_bounds__(256) void k_down(
    const float* __restrict__ x, const float* __restrict__ Wd,
    const float* __restrict__ bd,
    const float* __restrict__ Wa1, const float* __restrict__ Wg1,
    const float* __restrict__ Wa2, const float* __restrict__ Wg2,
    const float* __restrict__ Wup, const float* __restrict__ Wsc,
    ushortT* __restrict__ wsw, ushortT* __restrict__ h0w)
{
    const int t = threadIdx.x;
    if (blockIdx.x >= 512) {
        const int gid = (blockIdx.x - 512) * 256 + t, gs = 68 * 256;
        tpose(Wa1, wsw + WS_WAT1, 64, 64, 72, gid, gs);
        tpose(Wg1, wsw + WS_WGT1, 64, 64, 72, gid, gs);
        tpose(Wa2, wsw + WS_WAT2, 128, 128, 136, gid, gs);
        tpose(Wg2, wsw + WS_WGT2, 128, 128, 136, gid, gs);
        tpose(Wup, wsw + WS_WUPT, 128, 128, 136, gid, gs);
        tpose(Wsc, wsw + WS_WSCT, 64, 128, 72, gid, gs);
        return;
    }

    __shared__ __align__(16) ushortT Al[128 * 72];
    __shared__ __align__(16) ushortT Bl[32 * 72];
    const int rowBase = blockIdx.x * 128;

    {   // stage A: x rows -> bf16 LDS
        const int r = t >> 1, c0 = (t & 1) * 32;
        unsigned* dst = (unsigned*)Al + r * 36 + (c0 >> 1);
        const float* src = &x[(size_t)(rowBase + r) * 64 + c0];
#pragma unroll
        for (int j = 0; j < 32; j += 4) {
            const float4 v = *reinterpret_cast<const float4*>(src + j);
            dst[(j >> 1) + 0] = pack2(v.x, v.y);
            dst[(j >> 1) + 1] = pack2(v.z, v.w);
        }
        // stage B: Wd^T [32 n][64 k] bf16 (transpose on the fly)
        const int n = t >> 3, kc = (t & 7) * 8;
        float v[8];
#pragma unroll
        for (int j = 0; j < 8; ++j) v[j] = Wd[(size_t)(kc + j) * 32 + n];
        uint4 p;
        p.x = pack2(v[0], v[1]); p.y = pack2(v[2], v[3]);
        p.z = pack2(v[4], v[5]); p.w = pack2(v[6], v[7]);
        *(uint4*)((unsigned*)Bl + n * 36 + (kc >> 1)) = p;
    }
    __syncthreads();

    const int lane = t & 63, w = t >> 6, quad = lane >> 4, c16 = lane & 15;
    f32x4 acc[2][2];
#pragma unroll
    for (int mt = 0; mt < 2; ++mt)
#pragma unroll
        for (int nt = 0; nt < 2; ++nt)
#pragma unroll
            for (int r = 0; r < 4; ++r) acc[mt][nt][r] = 0.f;
#pragma unroll
    for (int ks = 0; ks < 2; ++ks) {
        bf16x8 a[2], b[2];
#pragma unroll
        for (int mt = 0; mt < 2; ++mt)
            a[mt] = *(const bf16x8*)&Al[(w * 32 + mt * 16 + c16) * 72 + ks * 32 + quad * 8];
#pragma unroll
        for (int nt = 0; nt < 2; ++nt)
            b[nt] = *(const bf16x8*)&Bl[(nt * 16 + c16) * 72 + ks * 32 + quad * 8];
#pragma unroll
        for (int mt = 0; mt < 2; ++mt)
#pragma unroll
            for (int nt = 0; nt < 2; ++nt) MFMA16(acc[mt][nt], a[mt], b[nt]);
    }
#pragma unroll
    for (int nt = 0; nt < 2; ++nt) {
        const int col = nt * 16 + c16;
        const float bias = bd[col];
#pragma unroll
        for (int mt = 0; mt < 2; ++mt)
#pragma unroll
            for (int r = 0; r < 4; ++r) {
                const int row = rowBase + w * 32 + mt * 16 + quad * 4 + r;
                h0w[(size_t)row * 32 + col] = f2bf(fmaxf(acc[mt][nt][r] + bias, 0.f));
            }
    }
}

// ---------------------------------------------------------------------------
// k_conv1: 4 nodes/block (4096 blocks); wave w owns node w (16 edges = one
// M-tile). F=[64 edges][64 ch] bf16 (9.2 KB) -> 8 blocks/CU (thread-capped).
// ---------------------------------------------------------------------------
__global__ __launch_bounds__(256) void k_conv1(
    const ushortT* __restrict__ h0w, const float* __restrict__ pos,
    const int* __restrict__ idx1, const int* __restrict__ src1,
    const float* __restrict__ Wpp, const float* __restrict__ bpp,
    const ushortT* __restrict__ wsw, const float* __restrict__ batt,
    const float* __restrict__ bg, ushortT* __restrict__ h1w)
{
    __shared__ __align__(16) ushortT Fl[64 * 72];     // 9.2 KB
    __shared__ __align__(16) ushortT A2ls[16 * 72];   // 2.3 KB
    __shared__ float Pl[352];                         // Wpp1 [10][32] + bpp1[32]
    const int t = threadIdx.x;
    const int d0 = blockIdx.x * 4;

    for (int i = t; i < 352; i += 256) Pl[i] = (i < 320) ? Wpp[i] : bpp[i - 320];
    for (int i = t; i < 432; i += 256) ((unsigned*)A2ls)[144 + i] = 0;  // pad rows 4..15

    {   // build F: 4 threads/edge
        const int e = t >> 2, q = t & 3;
        const int g = e >> 4;
        const int s = src1[(d0 + g) * 16 + (e & 15)];
        // copy h0 row (32 bf16 = 4 uint4): 1 uint4/thread
        ((uint4*)((unsigned*)Fl + e * 36))[q] =
            ((const uint4*)((const unsigned*)h0w + (size_t)s * 16))[q];

        const int pin = idx1[d0 + g];
        const float pix = pos[pin * 3 + 0], piy = pos[pin * 3 + 1], piz = pos[pin * 3 + 2];
        const float pjx = pos[s * 3 + 0],  pjy = pos[s * 3 + 1],  pjz = pos[s * 3 + 2];
        const float vx = pix - pjx, vy = piy - pjy, vz = piz - pjz;
        const float dij = sqrtf(vx * vx + vy * vy + vz * vz);
        const float rel[10] = {pix, piy, piz, pjx, pjy, pjz, vx, vy, vz, dij};
        __syncthreads();    // Pl ready (uniform)
        const int c0 = q * 8;   // 8 pp channels per thread
#pragma unroll
        for (int c = 0; c < 8; c += 2) {
            float a0 = Pl[320 + c0 + c], a1 = Pl[320 + c0 + c + 1];
#pragma unroll
            for (int i = 0; i < 10; ++i) {
                a0 += rel[i] * Pl[i * 32 + c0 + c];
                a1 += rel[i] * Pl[i * 32 + c0 + c + 1];
            }
            ((unsigned*)Fl)[(e * 72 + 32 + c0 + c) >> 1] = pack2(fmaxf(a0, 0.f), fmaxf(a1, 0.f));
        }
    }
    __syncthreads();

    const int lane = t & 63, w = t >> 6, quad = lane >> 4, c16 = lane & 15;
    const ushortT* WB = wsw + WS_WAT1;    // Watt1^T [64][72]
    f32x4 acc[4];
#pragma unroll
    for (int nt = 0; nt < 4; ++nt)
#pragma unroll
        for (int r = 0; r < 4; ++r) acc[nt][r] = 0.f;
#pragma unroll
    for (int ks = 0; ks < 2; ++ks) {
        const bf16x8 a = *(const bf16x8*)&Fl[(w * 16 + c16) * 72 + ks * 32 + quad * 8];
#pragma unroll
        for (int nt = 0; nt < 4; ++nt) {
            const bf16x8 b = *(const bf16x8*)&WB[(nt * 16 + c16) * 72 + ks * 32 + quad * 8];
            MFMA16(acc[nt], a, b);
        }
    }
    float bcol[4];
#pragma unroll
    for (int nt = 0; nt < 4; ++nt) bcol[nt] = batt[nt * 16 + c16];

    float rs[4];
#pragma unroll
    for (int r = 0; r < 4; ++r) {
        float sm = 0.f;
#pragma unroll
        for (int nt = 0; nt < 4; ++nt) {
            const float a = fmaxf(acc[nt][r] + bcol[nt], 0.f);
            acc[nt][r] = __expf(a - SMAX_SHIFT);
            sm += acc[nt][r];
        }
        sm += __shfl_xor(sm, 1);
        sm += __shfl_xor(sm, 2);
        sm += __shfl_xor(sm, 4);
        sm += __shfl_xor(sm, 8);
        rs[r] = 1.f / sm;
    }
#pragma unroll
    for (int nt = 0; nt < 4; ++nt) {
        float v = 0.f;
#pragma unroll
        for (int r = 0; r < 4; ++r) {
            const float fv = bfu2f(Fl[(w * 16 + quad * 4 + r) * 72 + nt * 16 + c16]);
            v += acc[nt][r] * rs[r] * fv;
        }
        v += __shfl_xor(v, 16);
        v += __shfl_xor(v, 32);
        if (lane < 16)
            A2ls[w * 72 + nt * 16 + c16] = f2bf(v);   // row w (node w)
    }
    __syncthreads();

    // ---- fused global_nn: h1 = relu(agg @ Wg1 + bg1); wave w = N-tile w ----
    {
        const ushortT* GB = wsw + WS_WGT1;
        f32x4 acc2 = {0.f, 0.f, 0.f, 0.f};
#pragma unroll
        for (int ks = 0; ks < 2; ++ks) {
            const bf16x8 a = *(const bf16x8*)&A2ls[c16 * 72 + ks * 32 + quad * 8];
            const bf16x8 b = *(const bf16x8*)&GB[(w * 16 + c16) * 72 + ks * 32 + quad * 8];
            MFMA16(acc2, a, b);
        }
        const int col = w * 16 + c16;
        const float bias = bg[col];
        if (quad == 0) {    // rows 0..3 valid (nodes d0..d0+3)
#pragma unroll
            for (int r = 0; r < 4; ++r)
                h1w[(size_t)(d0 + r) * 64 + col] = f2bf(fmaxf(acc2[r] + bias, 0.f));
        }
    }
}

// ---------------------------------------------------------------------------
// k_conv2f: 4 nodes/block (2048 blocks); wave w owns node w. F=[64][136]
// (17.4 KB, total ~29 KB -> 5 blocks/CU). Fused post GEMMs at M=16 (4 valid).
// ---------------------------------------------------------------------------
__global__ __launch_bounds__(256) void k_conv2f(
    const ushortT* __restrict__ h1w, const float* __restrict__ pos,
    const float* __restrict__ x,
    const int* __restrict__ idx1, const int* __restrict__ idx2,
    const int* __restrict__ src2,
    const float* __restrict__ Wpp, const float* __restrict__ bpp,
    const ushortT* __restrict__ wsw, const float* __restrict__ batt,
    const float* __restrict__ bg, const float* __restrict__ bup,
    const float* __restrict__ bsc, float* __restrict__ out)
{
    __shared__ __align__(16) ushortT Fl[64 * 136];    // 17.4 KB
    __shared__ __align__(16) ushortT AGG[16 * 136];   // 4.3 KB (rows 4..15 pad)
    __shared__ __align__(16) ushortT H2[16 * 136];    // 4.3 KB
    __shared__ float Pl[704];                         // Wpp2 [10][64] + bpp2[64]
    const int t = threadIdx.x;
    const int d0 = blockIdx.x * 4;

    for (int i = t; i < 704; i += 256) Pl[i] = (i < 640) ? Wpp[i] : bpp[i - 640];
    for (int i = t; i < 816; i += 256) ((unsigned*)AGG)[272 + i] = 0;   // pad rows 4..15

    {   // build F: 4 threads/edge
        const int e = t >> 2, q = t & 3;
        const int g = e >> 4;
        const int s = src2[(d0 + g) * 16 + (e & 15)];
        // copy h1 row (64 bf16 = 8 uint4): 2 uint4/thread
        {
            const uint4* srcp = (const uint4*)((const unsigned*)h1w + (size_t)s * 32);
            uint4* dstp = (uint4*)((unsigned*)Fl + e * 68);
            dstp[q * 2 + 0] = srcp[q * 2 + 0];
            dstp[q * 2 + 1] = srcp[q * 2 + 1];
        }
        const int pin = idx1[idx2[d0 + g]];
        const int sn = idx1[s];
        const float pix = pos[pin * 3 + 0], piy = pos[pin * 3 + 1], piz = pos[pin * 3 + 2];
        const float pjx = pos[sn * 3 + 0],  pjy = pos[sn * 3 + 1],  pjz = pos[sn * 3 + 2];
        const float vx = pix - pjx, vy = piy - pjy, vz = piz - pjz;
        const float dij = sqrtf(vx * vx + vy * vy + vz * vz);
        const float rel[10] = {pix, piy, piz, pjx, pjy, pjz, vx, vy, vz, dij};
        __syncthreads();    // Pl ready (uniform)
        const int c0 = q * 16;  // 16 pp channels per thread
#pragma unroll
        for (int c = 0; c < 16; c += 2) {
            float a0 = Pl[640 + c0 + c], a1 = Pl[640 + c0 + c + 1];
#pragma unroll
            for (int i = 0; i < 10; ++i) {
                a0 += rel[i] * Pl[i * 64 + c0 + c];
                a1 += rel[i] * Pl[i * 64 + c0 + c + 1];
            }
            ((unsigned*)Fl)[(e * 136 + 64 + c0 + c) >> 1] = pack2(fmaxf(a0, 0.f), fmaxf(a1, 0.f));
        }
    }
    __syncthreads();

    const int lane = t & 63, w = t >> 6, quad = lane >> 4, c16 = lane & 15;
    const ushortT* WB = wsw + WS_WAT2;    // Watt2^T [128][136]
    f32x4 acc[8];
#pragma unroll
    for (int nt = 0; nt < 8; ++nt)
#pragma unroll
        for (int r = 0; r < 4; ++r) acc[nt][r] = 0.f;
#pragma unroll
    for (int ks = 0; ks < 4; ++ks) {
        const bf16x8 a = *(const bf16x8*)&Fl[(w * 16 + c16) * 136 + ks * 32 + quad * 8];
#pragma unroll
        for (int nt = 0; nt < 8; ++nt) {
            const bf16x8 b = *(const bf16x8*)&WB[(nt * 16 + c16) * 136 + ks * 32 + quad * 8];
            MFMA16(acc[nt], a, b);
        }
    }
    float bcol[8];
#pragma unroll
    for (int nt = 0; nt < 8; ++nt) bcol[nt] = batt[nt * 16 + c16];

    float rs[4];
#pragma unroll
    for (int r = 0; r < 4; ++r) {
        float sm = 0.f;
#pragma unroll
        for (int nt = 0; nt < 8; ++nt) {
            const float a = fmaxf(acc[nt][r] + bcol[nt], 0.f);
            acc[nt][r] = __expf(a - SMAX_SHIFT);
            sm += acc[nt][r];
        }
        sm += __shfl_xor(sm, 1);
        sm += __shfl_xor(sm, 2);
        sm += __shfl_xor(sm, 4);
        sm += __shfl_xor(sm, 8);
        rs[r] = 1.f / sm;
    }
#pragma unroll
    for (int nt = 0; nt < 8; ++nt) {
        float v = 0.f;
#pragma unroll
        for (int r = 0; r < 4; ++r) {
            const float fv = bfu2f(Fl[(w * 16 + quad * 4 + r) * 136 + nt * 16 + c16]);
            v += acc[nt][r] * rs[r] * fv;
        }
        v += __shfl_xor(v, 16);
        v += __shfl_xor(v, 32);
        if (lane < 16)
            AGG[w * 136 + nt * 16 + c16] = f2bf(v);   // row w (node w)
    }
    __syncthreads();

    // ======================= fused post: 3 chained GEMMs ====================
    // wave w handles column tiles {w*2, w*2+1}; M=16 (rows 0..3 valid)

    // ---- GEMM1: h2 = relu(agg @ Wg2 + bg2) -> H2 (LDS, A-layout) ----
    {
        const ushortT* GB = wsw + WS_WGT2;
        f32x4 g[2];
#pragma unroll
        for (int j = 0; j < 2; ++j)
#pragma unroll
            for (int r = 0; r < 4; ++r) g[j][r] = 0.f;
#pragma unroll
        for (int ks = 0; ks < 4; ++ks) {
            const bf16x8 a = *(const bf16x8*)&AGG[c16 * 136 + ks * 32 + quad * 8];
#pragma unroll
            for (int j = 0; j < 2; ++j) {
                const bf16x8 b = *(const bf16x8*)&GB[((w * 2 + j) * 16 + c16) * 136 + ks * 32 + quad * 8];
                MFMA16(g[j], a, b);
            }
        }
#pragma unroll
        for (int j = 0; j < 2; ++j) {
            const int col = (w * 2 + j) * 16 + c16;
            const float bias = bg[col];
#pragma unroll
            for (int r = 0; r < 4; ++r)
                H2[(quad * 4 + r) * 136 + col] = f2bf(fmaxf(g[j][r] + bias, 0.f));
        }
    }
    __syncthreads();

    // ---- GEMM2: u = relu(h2 @ Wup + bup), regs ----
    f32x4 u[2];
    {
        const ushortT* UB = wsw + WS_WUPT;
#pragma unroll
        for (int j = 0; j < 2; ++j)
#pragma unroll
            for (int r = 0; r < 4; ++r) u[j][r] = 0.f;
#pragma unroll
        for (int ks = 0; ks < 4; ++ks) {
            const bf16x8 a = *(const bf16x8*)&H2[c16 * 136 + ks * 32 + quad * 8];
#pragma unroll
            for (int j = 0; j < 2; ++j) {
                const bf16x8 b = *(const bf16x8*)&UB[((w * 2 + j) * 16 + c16) * 136 + ks * 32 + quad * 8];
                MFMA16(u[j], a, b);
            }
        }
#pragma unroll
        for (int j = 0; j < 2; ++j) {
            const float bias = bup[(w * 2 + j) * 16 + c16];
#pragma unroll
            for (int r = 0; r < 4; ++r) u[j][r] = fmaxf(u[j][r] + bias, 0.f);
        }
    }

    // ---- GEMM3: sc = relu(x2 @ Wsc + bsc); out = u + sc ----
    {
        const ushortT* SB = wsw + WS_WSCT;   // [128][72]
        const int pinx = idx1[idx2[d0 + (c16 & 3)]];
        const float* xrow = &x[(size_t)pinx * 64];
        f32x4 s[2];
#pragma unroll
        for (int j = 0; j < 2; ++j)
#pragma unroll
            for (int r = 0; r < 4; ++r) s[j][r] = 0.f;
#pragma unroll
        for (int ks = 0; ks < 2; ++ks) {
            const float4 v0 = *reinterpret_cast<const float4*>(xrow + ks * 32 + quad * 8);
            const float4 v1 = *reinterpret_cast<const float4*>(xrow + ks * 32 + quad * 8 + 4);
            union { bf16x8 v; unsigned u[4]; } a;
            a.u[0] = pack2(v0.x, v0.y); a.u[1] = pack2(v0.z, v0.w);
            a.u[2] = pack2(v1.x, v1.y); a.u[3] = pack2(v1.z, v1.w);
#pragma unroll
            for (int j = 0; j < 2; ++j) {
                const bf16x8 b = *(const bf16x8*)&SB[((w * 2 + j) * 16 + c16) * 72 + ks * 32 + quad * 8];
                MFMA16(s[j], a.v, b);
            }
        }
        if (quad == 0) {     // rows 0..3 valid (nodes d0..d0+3)
#pragma unroll
            for (int j = 0; j < 2; ++j) {
                const int col = (w * 2 + j) * 16 + c16;
                const float bias = bsc[col];
#pragma unroll
                for (int r = 0; r < 4; ++r) {
                    const float sc = fmaxf(s[j][r] + bias, 0.f);
                    out[(size_t)(d0 + r) * 128 + col] = u[j][r] + sc;  // both >=0
                }
            }
        }
    }
}

extern "C" void kernel_launch(void* const* d_in, const int* in_sizes, int n_in,
                              void* d_out, int out_size, void* d_ws, size_t ws_size,
                              hipStream_t stream)
{
    const float* x      = (const float*)d_in[0];
    const float* pos    = (const float*)d_in[1];
    const float* W_down = (const float*)d_in[2];
    const float* b_down = (const float*)d_in[3];
    const float* W_pp1  = (const float*)d_in[4];
    const float* b_pp1  = (const float*)d_in[5];
    const float* W_att1 = (const float*)d_in[6];
    const float* b_att1 = (const float*)d_in[7];
    const float* W_g1   = (const float*)d_in[8];
    const float* b_g1   = (const float*)d_in[9];
    const float* W_pp2  = (const float*)d_in[10];
    const float* b_pp2  = (const float*)d_in[11];
    const float* W_att2 = (const float*)d_in[12];
    const float* b_att2 = (const float*)d_in[13];
    const float* W_g2   = (const float*)d_in[14];
    const float* b_g2   = (const float*)d_in[15];
    const float* W_up   = (const float*)d_in[16];
    const float* b_up   = (const float*)d_in[17];
    const float* W_sc   = (const float*)d_in[18];
    const float* b_sc   = (const float*)d_in[19];
    const int* idx1 = (const int*)d_in[20];
    const int* idx2 = (const int*)d_in[21];
    const int* src1 = (const int*)d_in[22];
    const int* src2 = (const int*)d_in[24];

    ushortT* wsw = (ushortT*)d_ws;
    ushortT* h0w = wsw + WS_H0;
    ushortT* h1w = wsw + WS_H1;

    k_down  <<<512 + 68, 256, 0, stream>>>(x, W_down, b_down,
                                           W_att1, W_g1, W_att2, W_g2, W_up, W_sc,
                                           wsw, h0w);
    k_conv1 <<<NN1 / 4, 256, 0, stream>>>(h0w, pos, idx1, src1,
                                          W_pp1, b_pp1, wsw, b_att1, b_g1, h1w);
    k_conv2f<<<NN2 / 4, 256, 0, stream>>>(h1w, pos, x, idx1, idx2, src2,
                                          W_pp2, b_pp2, wsw, b_att2,
                                          b_g2, b_up, b_sc, (float*)d_out);
}

// Round 10
// 169.237 us; speedup vs baseline: 1.0658x; 1.0658x over previous
//
#include <hip/hip_runtime.h>

#define N_FULL 65536
#define NN1    16384
#define NN2    8192

typedef __attribute__((ext_vector_type(8))) short bf16x8;
typedef __attribute__((ext_vector_type(4))) float f32x4;
typedef unsigned short ushortT;

#define MFMA16(acc, a, b) acc = __builtin_amdgcn_mfma_f32_16x16x32_bf16(a, b, acc, 0, 0, 0)

#if __has_builtin(__builtin_amdgcn_cvt_pk_bf16_f32)
typedef __attribute__((ext_vector_type(2))) __bf16 bf16x2t;
static __device__ __forceinline__ unsigned pack2(float a, float b) {
    union { bf16x2t v; unsigned u; } c;
    c.v = __builtin_amdgcn_cvt_pk_bf16_f32(a, b);
    return c.u;
}
static __device__ __forceinline__ ushortT f2bf(float f) {
    union { bf16x2t v; ushortT s[2]; } c;
    c.v = __builtin_amdgcn_cvt_pk_bf16_f32(f, 0.f);
    return c.s[0];
}
#else
static __device__ __forceinline__ ushortT f2bf(float f) {
    union { float f; unsigned u; } v; v.f = f;
    unsigned r = v.u + 0x7FFFu + ((v.u >> 16) & 1u);
    return (ushortT)(r >> 16);
}
static __device__ __forceinline__ unsigned pack2(float a, float b) {
    return (unsigned)f2bf(a) | ((unsigned)f2bf(b) << 16);
}
#endif

static __device__ __forceinline__ float bfu2f(ushortT h) {
    union { unsigned u; float f; } v; v.u = (unsigned)h << 16; return v.f;
}

// ws layout (ushort units) — all byte offsets 16B-aligned
#define WS_WAT1  2304     /* [64][72]   */
#define WS_WGT1  6912     /* [64][72]   */
#define WS_WAT2  11520    /* [128][136] */
#define WS_WGT2  28928    /* [128][136] */
#define WS_WUPT  46336    /* [128][136] */
#define WS_WSCT  63744    /* [128][72]  */
#define WS_H0    73728    /* bf16 [65536][32] */
#define WS_H1    (WS_H0 + 65536u*32u)

// softmax fixed shift: softmax(a) == softmax(a - C); scores are relu'd O(10)
#define SMAX_SHIFT 24.0f

// ---------------------------------------------------------------------------
// weight transpose helper (runs in the prep-blocks of k_down)
// ---------------------------------------------------------------------------
static __device__ __forceinline__ void tpose(
    const float* __restrict__ src, ushortT* __restrict__ dst,
    int K, int N, int STR, int gid, int gs)
{
    for (int i = gid; i < K * N; i += gs) {
        const int n = i / K, k = i - n * K;
        dst[n * STR + k] = f2bf(src[(size_t)k * N + n]);
    }
}

// ---------------------------------------------------------------------------
// k_down (+prep): blocks <512: h0 = relu(x @ Wd + bd); blocks >=512: weight
// transposes for later kernels.
// ---------------------------------------------------------------------------
__global__ __launch_bounds__(256) void k_down(
    const float* __restrict__ x, const float* __restrict__ Wd,
    const float* __restrict__ bd,
    const float* __restrict__ Wa1, const float* __restrict__ Wg1,
    const float* __restrict__ Wa2, const float* __restrict__ Wg2,
    const float* __restrict__ Wup, const float* __restrict__ Wsc,
    ushortT* __restrict__ wsw, ushortT* __restrict__ h0w)
{
    const int t = threadIdx.x;
    if (blockIdx.x >= 512) {
        const int gid = (blockIdx.x - 512) * 256 + t, gs = 68 * 256;
        tpose(Wa1, wsw + WS_WAT1, 64, 64, 72, gid, gs);
        tpose(Wg1, wsw + WS_WGT1, 64, 64, 72, gid, gs);
        tpose(Wa2, wsw + WS_WAT2, 128, 128, 136, gid, gs);
        tpose(Wg2, wsw + WS_WGT2, 128, 128, 136, gid, gs);
        tpose(Wup, wsw + WS_WUPT, 128, 128, 136, gid, gs);
        tpose(Wsc, wsw + WS_WSCT, 64, 128, 72, gid, gs);
        return;
    }

    __shared__ __align__(16) ushortT Al[128 * 72];
    __shared__ __align__(16) ushortT Bl[32 * 72];
    const int rowBase = blockIdx.x * 128;

    {   // stage A: x rows -> bf16 LDS
        const int r = t >> 1, c0 = (t & 1) * 32;
        unsigned* dst = (unsigned*)Al + r * 36 + (c0 >> 1);
        const float* src = &x[(size_t)(rowBase + r) * 64 + c0];
#pragma unroll
        for (int j = 0; j < 32; j += 4) {
            const float4 v = *reinterpret_cast<const float4*>(src + j);
            dst[(j >> 1) + 0] = pack2(v.x, v.y);
            dst[(j >> 1) + 1] = pack2(v.z, v.w);
        }
        // stage B: Wd^T [32 n][64 k] bf16 (transpose on the fly)
        const int n = t >> 3, kc = (t & 7) * 8;
        float v[8];
#pragma unroll
        for (int j = 0; j < 8; ++j) v[j] = Wd[(size_t)(kc + j) * 32 + n];
        uint4 p;
        p.x = pack2(v[0], v[1]); p.y = pack2(v[2], v[3]);
        p.z = pack2(v[4], v[5]); p.w = pack2(v[6], v[7]);
        *(uint4*)((unsigned*)Bl + n * 36 + (kc >> 1)) = p;
    }
    __syncthreads();

    const int lane = t & 63, w = t >> 6, quad = lane >> 4, c16 = lane & 15;
    f32x4 acc[2][2];
#pragma unroll
    for (int mt = 0; mt < 2; ++mt)
#pragma unroll
        for (int nt = 0; nt < 2; ++nt)
#pragma unroll
            for (int r = 0; r < 4; ++r) acc[mt][nt][r] = 0.f;
#pragma unroll
    for (int ks = 0; ks < 2; ++ks) {
        bf16x8 a[2], b[2];
#pragma unroll
        for (int mt = 0; mt < 2; ++mt)
            a[mt] = *(const bf16x8*)&Al[(w * 32 + mt * 16 + c16) * 72 + ks * 32 + quad * 8];
#pragma unroll
        for (int nt = 0; nt < 2; ++nt)
            b[nt] = *(const bf16x8*)&Bl[(nt * 16 + c16) * 72 + ks * 32 + quad * 8];
#pragma unroll
        for (int mt = 0; mt < 2; ++mt)
#pragma unroll
            for (int nt = 0; nt < 2; ++nt) MFMA16(acc[mt][nt], a[mt], b[nt]);
    }
#pragma unroll
    for (int nt = 0; nt < 2; ++nt) {
        const int col = nt * 16 + c16;
        const float bias = bd[col];
#pragma unroll
        for (int mt = 0; mt < 2; ++mt)
#pragma unroll
            for (int r = 0; r < 4; ++r) {
                const int row = rowBase + w * 32 + mt * 16 + quad * 4 + r;
                h0w[(size_t)row * 32 + col] = f2bf(fmaxf(acc[mt][nt][r] + bias, 0.f));
            }
    }
}

// ---------------------------------------------------------------------------
// k_conv1: 512 threads, 8 nodes/block (2048 blocks). Wave w owns node w.
// F=[128 edges][64 ch] shared by 8 waves (18.4 KB). 4 blocks/CU thread-cap.
// ---------------------------------------------------------------------------
__global__ __launch_bounds__(512) void k_conv1(
    const ushortT* __restrict__ h0w, const float* __restrict__ pos,
    const int* __restrict__ idx1, const int* __restrict__ src1,
    const float* __restrict__ Wpp, const float* __restrict__ bpp,
    const ushortT* __restrict__ wsw, const float* __restrict__ batt,
    const float* __restrict__ bg, ushortT* __restrict__ h1w)
{
    __shared__ __align__(16) ushortT Fl[128 * 72];    // 18.4 KB
    __shared__ __align__(16) ushortT A2ls[16 * 72];   // 2.3 KB (rows 8..15 pad)
    __shared__ float Pl[352];                         // Wpp1 [10][32] + bpp1[32]
    const int t = threadIdx.x;
    const int d0 = blockIdx.x * 8;

    for (int i = t; i < 352; i += 512) Pl[i] = (i < 320) ? Wpp[i] : bpp[i - 320];
    for (int i = t; i < 288; i += 512) ((unsigned*)A2ls)[288 + i] = 0;  // pad rows 8..15

    {   // build F: 4 threads/edge (128 edges)
        const int e = t >> 2, q = t & 3;
        const int g = e >> 4;
        const int s = src1[(d0 + g) * 16 + (e & 15)];
        // copy h0 row (32 bf16 = 4 uint4): 1 uint4/thread
        ((uint4*)((unsigned*)Fl + e * 36))[q] =
            ((const uint4*)((const unsigned*)h0w + (size_t)s * 16))[q];

        const int pin = idx1[d0 + g];
        const float pix = pos[pin * 3 + 0], piy = pos[pin * 3 + 1], piz = pos[pin * 3 + 2];
        const float pjx = pos[s * 3 + 0],  pjy = pos[s * 3 + 1],  pjz = pos[s * 3 + 2];
        const float vx = pix - pjx, vy = piy - pjy, vz = piz - pjz;
        const float dij = sqrtf(vx * vx + vy * vy + vz * vz);
        const float rel[10] = {pix, piy, piz, pjx, pjy, pjz, vx, vy, vz, dij};
        __syncthreads();    // Pl ready (uniform)
        const int c0 = q * 8;   // 8 pp channels per thread
#pragma unroll
        for (int c = 0; c < 8; c += 2) {
            float a0 = Pl[320 + c0 + c], a1 = Pl[320 + c0 + c + 1];
#pragma unroll
            for (int i = 0; i < 10; ++i) {
                a0 += rel[i] * Pl[i * 32 + c0 + c];
                a1 += rel[i] * Pl[i * 32 + c0 + c + 1];
            }
            ((unsigned*)Fl)[(e * 72 + 32 + c0 + c) >> 1] = pack2(fmaxf(a0, 0.f), fmaxf(a1, 0.f));
        }
    }
    __syncthreads();

    const int lane = t & 63, w = t >> 6, quad = lane >> 4, c16 = lane & 15;
    const ushortT* WB = wsw + WS_WAT1;    // Watt1^T [64][72]
    f32x4 acc[4];
#pragma unroll
    for (int nt = 0; nt < 4; ++nt)
#pragma unroll
        for (int r = 0; r < 4; ++r) acc[nt][r] = 0.f;
#pragma unroll
    for (int ks = 0; ks < 2; ++ks) {
        const bf16x8 a = *(const bf16x8*)&Fl[(w * 16 + c16) * 72 + ks * 32 + quad * 8];
#pragma unroll
        for (int nt = 0; nt < 4; ++nt) {
            const bf16x8 b = *(const bf16x8*)&WB[(nt * 16 + c16) * 72 + ks * 32 + quad * 8];
            MFMA16(acc[nt], a, b);
        }
    }
    float bcol[4];
#pragma unroll
    for (int nt = 0; nt < 4; ++nt) bcol[nt] = batt[nt * 16 + c16];

    float rs[4];
#pragma unroll
    for (int r = 0; r < 4; ++r) {
        float sm = 0.f;
#pragma unroll
        for (int nt = 0; nt < 4; ++nt) {
            const float a = fmaxf(acc[nt][r] + bcol[nt], 0.f);
            acc[nt][r] = __expf(a - SMAX_SHIFT);
            sm += acc[nt][r];
        }
        sm += __shfl_xor(sm, 1);
        sm += __shfl_xor(sm, 2);
        sm += __shfl_xor(sm, 4);
        sm += __shfl_xor(sm, 8);
        rs[r] = 1.f / sm;
    }
#pragma unroll
    for (int nt = 0; nt < 4; ++nt) {
        float v = 0.f;
#pragma unroll
        for (int r = 0; r < 4; ++r) {
            const float fv = bfu2f(Fl[(w * 16 + quad * 4 + r) * 72 + nt * 16 + c16]);
            v += acc[nt][r] * rs[r] * fv;
        }
        v += __shfl_xor(v, 16);
        v += __shfl_xor(v, 32);
        if (lane < 16)
            A2ls[w * 72 + nt * 16 + c16] = f2bf(v);   // row w (node w)
    }
    __syncthreads();

    // ---- fused global_nn: h1 = relu(agg @ Wg1 + bg1); waves 0..3 = N-tiles ----
    if (w < 4) {
        const ushortT* GB = wsw + WS_WGT1;
        f32x4 acc2 = {0.f, 0.f, 0.f, 0.f};
#pragma unroll
        for (int ks = 0; ks < 2; ++ks) {
            const bf16x8 a = *(const bf16x8*)&A2ls[c16 * 72 + ks * 32 + quad * 8];
            const bf16x8 b = *(const bf16x8*)&GB[(w * 16 + c16) * 72 + ks * 32 + quad * 8];
            MFMA16(acc2, a, b);
        }
        const int col = w * 16 + c16;
        const float bias = bg[col];
        if (quad < 2) {    // rows 0..7 valid (nodes d0..d0+7)
#pragma unroll
            for (int r = 0; r < 4; ++r) {
                const int row = quad * 4 + r;
                h1w[(size_t)(d0 + row) * 64 + col] = f2bf(fmaxf(acc2[r] + bias, 0.f));
            }
        }
    }
}

// ---------------------------------------------------------------------------
// k_conv2f: 512 threads, 8 nodes/block (1024 blocks). Wave w owns node w.
// F=[128 edges][128 ch] shared by 8 waves; LDS ~46 KB -> 3 blocks/CU =
// 24 waves/CU. Fused post: wave w owns column tile w (8 tiles = 128 cols).
// ---------------------------------------------------------------------------
__global__ __launch_bounds__(512) void k_conv2f(
    const ushortT* __restrict__ h1w, const float* __restrict__ pos,
    const float* __restrict__ x,
    const int* __restrict__ idx1, const int* __restrict__ idx2,
    const int* __restrict__ src2,
    const float* __restrict__ Wpp, const float* __restrict__ bpp,
    const ushortT* __restrict__ wsw, const float* __restrict__ batt,
    const float* __restrict__ bg, const float* __restrict__ bup,
    const float* __restrict__ bsc, float* __restrict__ out)
{
    __shared__ __align__(16) ushortT Fl[128 * 136];   // 34.8 KB
    __shared__ __align__(16) ushortT AGG[16 * 136];   // 4.3 KB (rows 8..15 pad)
    __shared__ __align__(16) ushortT H2[16 * 136];    // 4.3 KB
    __shared__ float Pl[704];                         // Wpp2 [10][64] + bpp2[64]
    const int t = threadIdx.x;
    const int d0 = blockIdx.x * 8;

    for (int i = t; i < 704; i += 512) Pl[i] = (i < 640) ? Wpp[i] : bpp[i - 640];
    for (int i = t; i < 544; i += 512) ((unsigned*)AGG)[544 + i] = 0;   // pad rows 8..15

    {   // build F: 4 threads/edge (128 edges)
        const int e = t >> 2, q = t & 3;
        const int g = e >> 4;
        const int s = src2[(d0 + g) * 16 + (e & 15)];
        // copy h1 row (64 bf16 = 8 uint4): 2 uint4/thread
        {
            const uint4* srcp = (const uint4*)((const unsigned*)h1w + (size_t)s * 32);
            uint4* dstp = (uint4*)((unsigned*)Fl + e * 68);
            dstp[q * 2 + 0] = srcp[q * 2 + 0];
            dstp[q * 2 + 1] = srcp[q * 2 + 1];
        }
        const int pin = idx1[idx2[d0 + g]];
        const int sn = idx1[s];
        const float pix = pos[pin * 3 + 0], piy = pos[pin * 3 + 1], piz = pos[pin * 3 + 2];
        const float pjx = pos[sn * 3 + 0],  pjy = pos[sn * 3 + 1],  pjz = pos[sn * 3 + 2];
        const float vx = pix - pjx, vy = piy - pjy, vz = piz - pjz;
        const float dij = sqrtf(vx * vx + vy * vy + vz * vz);
        const float rel[10] = {pix, piy, piz, pjx, pjy, pjz, vx, vy, vz, dij};
        __syncthreads();    // Pl ready (uniform)
        const int c0 = q * 16;  // 16 pp channels per thread
#pragma unroll
        for (int c = 0; c < 16; c += 2) {
            float a0 = Pl[640 + c0 + c], a1 = Pl[640 + c0 + c + 1];
#pragma unroll
            for (int i = 0; i < 10; ++i) {
                a0 += rel[i] * Pl[i * 64 + c0 + c];
                a1 += rel[i] * Pl[i * 64 + c0 + c + 1];
            }
            ((unsigned*)Fl)[(e * 136 + 64 + c0 + c) >> 1] = pack2(fmaxf(a0, 0.f), fmaxf(a1, 0.f));
        }
    }
    __syncthreads();

    const int lane = t & 63, w = t >> 6, quad = lane >> 4, c16 = lane & 15;
    const ushortT* WB = wsw + WS_WAT2;    // Watt2^T [128][136]
    f32x4 acc[8];
#pragma unroll
    for (int nt = 0; nt < 8; ++nt)
#pragma unroll
        for (int r = 0; r < 4; ++r) acc[nt][r] = 0.f;
#pragma unroll
    for (int ks = 0; ks < 4; ++ks) {
        const bf16x8 a = *(const bf16x8*)&Fl[(w * 16 + c16) * 136 + ks * 32 + quad * 8];
#pragma unroll
        for (int nt = 0; nt < 8; ++nt) {
            const bf16x8 b = *(const bf16x8*)&WB[(nt * 16 + c16) * 136 + ks * 32 + quad * 8];
            MFMA16(acc[nt], a, b);
        }
    }
    float bcol[8];
#pragma unroll
    for (int nt = 0; nt < 8; ++nt) bcol[nt] = batt[nt * 16 + c16];

    float rs[4];
#pragma unroll
    for (int r = 0; r < 4; ++r) {
        float sm = 0.f;
#pragma unroll
        for (int nt = 0; nt < 8; ++nt) {
            const float a = fmaxf(acc[nt][r] + bcol[nt], 0.f);
            acc[nt][r] = __expf(a - SMAX_SHIFT);
            sm += acc[nt][r];
        }
        sm += __shfl_xor(sm, 1);
        sm += __shfl_xor(sm, 2);
        sm += __shfl_xor(sm, 4);
        sm += __shfl_xor(sm, 8);
        rs[r] = 1.f / sm;
    }
#pragma unroll
    for (int nt = 0; nt < 8; ++nt) {
        float v = 0.f;
#pragma unroll
        for (int r = 0; r < 4; ++r) {
            const float fv = bfu2f(Fl[(w * 16 + quad * 4 + r) * 136 + nt * 16 + c16]);
            v += acc[nt][r] * rs[r] * fv;
        }
        v += __shfl_xor(v, 16);
        v += __shfl_xor(v, 32);
        if (lane < 16)
            AGG[w * 136 + nt * 16 + c16] = f2bf(v);   // row w (node w)
    }
    __syncthreads();

    // ======================= fused post: 3 chained GEMMs ====================
    // wave w owns column tile w; M=16 (rows 0..7 valid)

    // ---- GEMM1: h2 = relu(agg @ Wg2 + bg2) -> H2 (LDS, A-layout) ----
    {
        const ushortT* GB = wsw + WS_WGT2;
        f32x4 g = {0.f, 0.f, 0.f, 0.f};
#pragma unroll
        for (int ks = 0; ks < 4; ++ks) {
            const bf16x8 a = *(const bf16x8*)&AGG[c16 * 136 + ks * 32 + quad * 8];
            const bf16x8 b = *(const bf16x8*)&GB[(w * 16 + c16) * 136 + ks * 32 + quad * 8];
            MFMA16(g, a, b);
        }
        const int col = w * 16 + c16;
        const float bias = bg[col];
#pragma unroll
        for (int r = 0; r < 4; ++r)
            H2[(quad * 4 + r) * 136 + col] = f2bf(fmaxf(g[r] + bias, 0.f));
    }
    __syncthreads();

    // ---- GEMM2: u = relu(h2 @ Wup + bup), regs ----
    f32x4 u = {0.f, 0.f, 0.f, 0.f};
    {
        const ushortT* UB = wsw + WS_WUPT;
#pragma unroll
        for (int ks = 0; ks < 4; ++ks) {
            const bf16x8 a = *(const bf16x8*)&H2[c16 * 136 + ks * 32 + quad * 8];
            const bf16x8 b = *(const bf16x8*)&UB[(w * 16 + c16) * 136 + ks * 32 + quad * 8];
            MFMA16(u, a, b);
        }
        const float bias = bup[w * 16 + c16];
#pragma unroll
        for (int r = 0; r < 4; ++r) u[r] = fmaxf(u[r] + bias, 0.f);
    }

    // ---- GEMM3: sc = relu(x2 @ Wsc + bsc); out = u + sc ----
    {
        const ushortT* SB = wsw + WS_WSCT;   // [128][72]
        const int pinx = idx1[idx2[d0 + (c16 & 7)]];
        const float* xrow = &x[(size_t)pinx * 64];
        f32x4 s = {0.f, 0.f, 0.f, 0.f};
#pragma unroll
        for (int ks = 0; ks < 2; ++ks) {
            const float4 v0 = *reinterpret_cast<const float4*>(xrow + ks * 32 + quad * 8);
            const float4 v1 = *reinterpret_cast<const float4*>(xrow + ks * 32 + quad * 8 + 4);
            union { bf16x8 v; unsigned u[4]; } a;
            a.u[0] = pack2(v0.x, v0.y); a.u[1] = pack2(v0.z, v0.w);
            a.u[2] = pack2(v1.x, v1.y); a.u[3] = pack2(v1.z, v1.w);
            const bf16x8 b = *(const bf16x8*)&SB[(w * 16 + c16) * 72 + ks * 32 + quad * 8];
            MFMA16(s, a.v, b);
        }
        if (quad < 2) {      // rows 0..7 valid (nodes d0..d0+7)
            const int col = w * 16 + c16;
            const float bias = bsc[col];
#pragma unroll
            for (int r = 0; r < 4; ++r) {
                const float sc = fmaxf(s[r] + bias, 0.f);
                out[(size_t)(d0 + quad * 4 + r) * 128 + col] = u[r] + sc;  // both >=0
            }
        }
    }
}

extern "C" void kernel_launch(void* const* d_in, const int* in_sizes, int n_in,
                              void* d_out, int out_size, void* d_ws, size_t ws_size,
                              hipStream_t stream)
{
    const float* x      = (const float*)d_in[0];
    const float* pos    = (const float*)d_in[1];
    const float* W_down = (const float*)d_in[2];
    const float* b_down = (const float*)d_in[3];
    const float* W_pp1  = (const float*)d_in[4];
    const float* b_pp1  = (const float*)d_in[5];
    const float* W_att1 = (const float*)d_in[6];
    const float* b_att1 = (const float*)d_in[7];
    const float* W_g1   = (const float*)d_in[8];
    const float* b_g1   = (const float*)d_in[9];
    const float* W_pp2  = (const float*)d_in[10];
    const float* b_pp2  = (const float*)d_in[11];
    const float* W_att2 = (const float*)d_in[12];
    const float* b_att2 = (const float*)d_in[13];
    const float* W_g2   = (const float*)d_in[14];
    const float* b_g2   = (const float*)d_in[15];
    const float* W_up   = (const float*)d_in[16];
    const float* b_up   = (const float*)d_in[17];
    const float* W_sc   = (const float*)d_in[18];
    const float* b_sc   = (const float*)d_in[19];
    const int* idx1 = (const int*)d_in[20];
    const int* idx2 = (const int*)d_in[21];
    const int* src1 = (const int*)d_in[22];
    const int* src2 = (const int*)d_in[24];

    ushortT* wsw = (ushortT*)d_ws;
    ushortT* h0w = wsw + WS_H0;
    ushortT* h1w = wsw + WS_H1;

    k_down  <<<512 + 68, 256, 0, stream>>>(x, W_down, b_down,
                                           W_att1, W_g1, W_att2, W_g2, W_up, W_sc,
                                           wsw, h0w);
    k_conv1 <<<NN1 / 8, 512, 0, stream>>>(h0w, pos, idx1, src1,
                                          W_pp1, b_pp1, wsw, b_att1, b_g1, h1w);
    k_conv2f<<<NN2 / 8, 512, 0, stream>>>(h1w, pos, x, idx1, idx2, src2,
                                          W_pp2, b_pp2, wsw, b_att2,
                                          b_g2, b_up, b_sc, (float*)d_out);
}